// Round 13
// baseline (237.565 us; speedup 1.0000x reference)
//
#include <hip/hip_runtime.h>

// ---------------------------------------------------------------------------
// GCN 3-layer fused pipeline for MI355X.
//   GEMM1: H1 = x @ W1 (bf16, MFMA)
//   AGGMM1: per 64-node block: agg(H1)+BN+relu -> LDS tile -> @W2 -> H2
//   AGGMM2: agg(H2)+BN+relu -> LDS tile -> @W3 -> H3 (N x 64)
//   AGG3:   agg(H3) + b3 -> d_out (f32)
// CSR: col-only (4B/edge); weights recomputed in agg from L2-resident dinv.
// 9 dispatches total.
// ---------------------------------------------------------------------------

#define SCAN_CHUNK 1024
#define NCHUNK 256   // edge chunks (hist/scatter blocks)
#define BSHIFT 8     // dsts per bucket = 256
#define BWID 256
#define ECAP 8192    // LDS col stage capacity per bucket (mean ~4100)

typedef __attribute__((ext_vector_type(8))) short bf16x8;
typedef __attribute__((ext_vector_type(4))) float f32x4;

__device__ __forceinline__ float blo(unsigned p) { return __uint_as_float(p << 16); }
__device__ __forceinline__ float bhi(unsigned p) { return __uint_as_float(p & 0xffff0000u); }
__device__ __forceinline__ unsigned short f2b(float f) {
  unsigned u = __float_as_uint(f);
  unsigned r = (u + 0x7fffu + ((u >> 16) & 1u)) >> 16;  // RTNE
  return (unsigned short)r;
}

// ---- pass A: per-chunk bucket histogram + fused weight prep ---------------
__global__ __launch_bounds__(256) void histprep_kernel(
    const int* __restrict__ ei32, const long long* __restrict__ ei64,
    int* __restrict__ counts, int E, int nbk,
    const float* __restrict__ W1, const float* __restrict__ W2,
    const float* __restrict__ W3,
    const float* __restrict__ b1, const float* __restrict__ g1,
    const float* __restrict__ be1, const float* __restrict__ m1,
    const float* __restrict__ v1,
    const float* __restrict__ b2, const float* __restrict__ g2,
    const float* __restrict__ be2, const float* __restrict__ m2,
    const float* __restrict__ v2,
    unsigned short* __restrict__ Wt1, unsigned short* __restrict__ Wt2,
    unsigned short* __restrict__ Wt3,
    float* __restrict__ sc1, float* __restrict__ sh1,
    float* __restrict__ sc2, float* __restrict__ sh2) {
  __shared__ int hist[BWID];
  __shared__ int s_is32;
  int k = blockIdx.x, t = threadIdx.x;
  if (k >= NCHUNK) {  // weight-prep tail
    int i = (k - NCHUNK) * 256 + t;
    if (i < 16384) {
      int kk = i >> 7, c = i & 127;
      Wt1[c * 128 + kk] = f2b(W1[i]);
    } else if (i < 32768) {
      int j = i - 16384; int kk = j >> 7, c = j & 127;
      Wt2[c * 128 + kk] = f2b(W2[j]);
    } else if (i < 40960) {
      int j = i - 32768; int kk = j >> 6, c = j & 63;
      Wt3[c * 128 + kk] = f2b(W3[j]);
    } else if (i < 41088) {
      int c = i - 40960;
      float s = g1[c] * rsqrtf(v1[c] + 1e-5f);
      sc1[c] = s; sh1[c] = (b1[c] - m1[c]) * s + be1[c];
    } else if (i < 41216) {
      int c = i - 41088;
      float s = g2[c] * rsqrtf(v2[c] + 1e-5f);
      sc2[c] = s; sh2[c] = (b2[c] - m2[c]) * s + be2[c];
    }
    return;
  }
  hist[t] = 0;
  if (t == 0) s_is32 = 0;
  int CH = (E + NCHUNK - 1) / NCHUNK;
  int e0 = k * CH, e1 = min(e0 + CH, E);
  __syncthreads();
  // int64 data: odd words are high halves == 0; int32: random node ids.
  if (t < 64 && e0 + t < E && ei32[2 * (e0 + t) + 1] != 0) atomicOr(&s_is32, 1);
  __syncthreads();
  int is32 = s_is32;
  for (int e = e0 + t; e < e1; e += 256) {
    int d = is32 ? ei32[E + e] : (int)ei64[E + e];
    atomicAdd(&hist[d >> BSHIFT], 1);
  }
  __syncthreads();
  if (t < nbk) counts[t * NCHUNK + k] = hist[t];
}

// ---- scan: partial sums ----------------------------------------------------
__global__ __launch_bounds__(256) void scan_partial_kernel(
    const int* __restrict__ src, int* __restrict__ bsum, int n) {
  __shared__ int wsum[4];
  int b = blockIdx.x, t = threadIdx.x;
  int lane = t & 63, wv = t >> 6;
  int i0 = b * SCAN_CHUNK + t * 4;
  int4 d4 = make_int4(0, 0, 0, 0);
  if (i0 + 3 < n) d4 = *(const int4*)&src[i0];
  else {
    if (i0 < n) d4.x = src[i0];
    if (i0 + 1 < n) d4.y = src[i0 + 1];
    if (i0 + 2 < n) d4.z = src[i0 + 2];
  }
  int s = d4.x + d4.y + d4.z + d4.w;
#pragma unroll
  for (int off = 32; off; off >>= 1) s += __shfl_xor(s, off);
  if (lane == 0) wsum[wv] = s;
  __syncthreads();
  if (t == 0) bsum[b] = wsum[0] + wsum[1] + wsum[2] + wsum[3];
}

// ---- scan: write (inline bsum scan) ---------------------------------------
__global__ __launch_bounds__(256) void scan_write_kernel(
    const int* __restrict__ src, const int* __restrict__ bsum,
    int* __restrict__ outp, int n, int nb) {
  __shared__ int woff[4];
  __shared__ int s_boff;
  int b = blockIdx.x, t = threadIdx.x;
  int lane = t & 63, wv = t >> 6;
  if (t < 64) {
    int v = (t < nb) ? bsum[t] : 0;
    int ic = v;
#pragma unroll
    for (int off = 1; off < 64; off <<= 1) {
      int u = __shfl_up(ic, off);
      if (t >= off) ic += u;
    }
    if (t == b) s_boff = ic - v;
    if (b == nb - 1 && t == 63) outp[n] = ic;  // total
  }
  int i0 = b * SCAN_CHUNK + t * 4;
  int4 d4 = make_int4(0, 0, 0, 0);
  if (i0 + 3 < n) d4 = *(const int4*)&src[i0];
  else {
    if (i0 < n) d4.x = src[i0];
    if (i0 + 1 < n) d4.y = src[i0 + 1];
    if (i0 + 2 < n) d4.z = src[i0 + 2];
  }
  int tsum = d4.x + d4.y + d4.z + d4.w;
  int inc = tsum;
#pragma unroll
  for (int off = 1; off < 64; off <<= 1) {
    int u = __shfl_up(inc, off);
    if (lane >= off) inc += u;
  }
  if (lane == 63) woff[wv] = inc;
  __syncthreads();
  if (t == 0) {
    int r = 0;
#pragma unroll
    for (int w = 0; w < 4; ++w) { int sw = woff[w]; woff[w] = r; r += sw; }
  }
  __syncthreads();
  int p = inc - tsum + woff[wv] + s_boff;
  int dg[4] = {d4.x, d4.y, d4.z, d4.w};
#pragma unroll
  for (int j = 0; j < 4; ++j) {
    int i = i0 + j;
    if (i < n) outp[i] = p;
    p += dg[j];
  }
}

// ---- pass C: scatter packed (src | dst_low<<20) into bucketed runs --------
__global__ __launch_bounds__(256) void bin_scatter_kernel(
    const int* __restrict__ ei32, const long long* __restrict__ ei64,
    const int* __restrict__ offs, unsigned* __restrict__ pairs, int E, int nbk) {
  __shared__ int cur[BWID];
  __shared__ int s_is32;
  int k = blockIdx.x, t = threadIdx.x;
  if (t < nbk) cur[t] = offs[t * NCHUNK + k];
  if (t == 0) s_is32 = 0;
  int CH = (E + NCHUNK - 1) / NCHUNK;
  int e0 = k * CH, e1 = min(e0 + CH, E);
  __syncthreads();
  if (t < 64 && e0 + t < E && ei32[2 * (e0 + t) + 1] != 0) atomicOr(&s_is32, 1);
  __syncthreads();
  int is32 = s_is32;
  for (int e = e0 + t; e < e1; e += 256) {
    int s, d;
    if (is32) { s = ei32[e]; d = ei32[E + e]; }
    else      { s = (int)ei64[e]; d = (int)ei64[E + e]; }
    int pos = atomicAdd(&cur[d >> BSHIFT], 1);
    pairs[pos] = (unsigned)s | ((unsigned)(d & (BWID - 1)) << 20);
  }
}

// ---- merged bucket pass: deg -> LDS scan -> rowptr/dinv -> col assembly ---
__global__ __launch_bounds__(256) void bucket_merged_kernel(
    const unsigned* __restrict__ pairs, const int* __restrict__ offs,
    int* __restrict__ rowptr, float* __restrict__ dinv,
    int* __restrict__ col, int E, int n, int nbk) {
  __shared__ int deg[BWID];
  __shared__ int cur[BWID];
  __shared__ int woff[4];
  __shared__ int stage_s[ECAP];
  int b = blockIdx.x, t = threadIdx.x;
  int lane = t & 63, wv = t >> 6;
  deg[t] = 0;
  __syncthreads();
  int basep = offs[b * NCHUNK];
  int endp = (b + 1 < nbk) ? offs[(b + 1) * NCHUNK] : E;
  for (int i = basep + t; i < endp; i += 256)
    atomicAdd(&deg[pairs[i] >> 20], 1);
  __syncthreads();
  int dg = deg[t];
  int inc = dg;
#pragma unroll
  for (int off = 1; off < 64; off <<= 1) {
    int u = __shfl_up(inc, off);
    if (lane >= off) inc += u;
  }
  if (lane == 63) woff[wv] = inc;
  __syncthreads();
  if (t == 0) {
    int r = 0;
#pragma unroll
    for (int w = 0; w < 4; ++w) { int sw = woff[w]; woff[w] = r; r += sw; }
  }
  __syncthreads();
  int exc = inc - dg + woff[wv];
  int idx = b * BWID + t;
  if (idx < n) {
    rowptr[idx] = basep + exc;
    dinv[idx] = rsqrtf((float)(dg + 1));  // +1 self loop
  }
  cur[t] = exc;
  __syncthreads();
  for (int i = basep + t; i < endp; i += 256) {
    unsigned p = pairs[i];
    int s = (int)(p & 0xFFFFFu);
    int dl = (int)(p >> 20);
    int pos = atomicAdd(&cur[dl], 1);
    if (pos < ECAP) stage_s[pos] = s;
    else col[basep + pos] = s;
  }
  __syncthreads();
  int nE = endp - basep;
  int lim = min(nE, ECAP);
  for (int i = t; i < lim; i += 256) col[basep + i] = stage_s[i];
  if (b == 0 && t == 0) rowptr[n] = E;
}

// ---- MFMA bf16 GEMM: Y[n x HOUT](bf16) = A[n x 128](f32) * Wt^T -----------
template <int HOUT>
__global__ __launch_bounds__(256) void mgemm_kernel(
    const float* __restrict__ A, const unsigned short* __restrict__ Wt,
    unsigned short* __restrict__ Y, int n) {
  constexpr int NT = HOUT;
  __shared__ unsigned char AsB[64 * 256];
  __shared__ unsigned char BsB[NT * 256];
  int t = threadIdx.x;
  int row0 = blockIdx.x * 64;

#pragma unroll
  for (int jj = 0; jj < 8; ++jj) {
    int f = t + 256 * jj; int r = f >> 5, kq = f & 31;
    float4 v = make_float4(0.f, 0.f, 0.f, 0.f);
    if (row0 + r < n) v = *(const float4*)&A[(size_t)(row0 + r) * 128 + kq * 4];
    unsigned two0 = (unsigned)f2b(v.x) | ((unsigned)f2b(v.y) << 16);
    unsigned two1 = (unsigned)f2b(v.z) | ((unsigned)f2b(v.w) << 16);
    uint2 o = make_uint2(two0, two1);
    *(uint2*)&AsB[r * 256 + ((kq * 8) ^ ((r & 15) << 4))] = o;
  }
#pragma unroll
  for (int jj = 0; jj < NT / 16; ++jj) {
    int f = t + 256 * jj; int c = f >> 4, kq = f & 15;
    uint4 v = *(const uint4*)&Wt[(size_t)c * 128 + kq * 8];
    *(uint4*)&BsB[c * 256 + ((kq * 16) ^ ((c & 15) << 4))] = v;
  }
  __syncthreads();

  int l = t & 63, wid = t >> 6;
  constexpr int WC = NT / 2;
  constexpr int NI = WC / 16;
  int wr = (wid >> 1) * 32, wc = (wid & 1) * WC;
  int lr = l & 15, lk = (l >> 4) * 16;

  f32x4 acc[2][NI] = {};
#pragma unroll
  for (int ks = 0; ks < 4; ++ks) {
    bf16x8 a[2], b[NI];
#pragma unroll
    for (int mi = 0; mi < 2; ++mi) {
      int r = wr + mi * 16 + lr;
      a[mi] = *(const bf16x8*)&AsB[r * 256 + ((ks * 64 + lk) ^ ((r & 15) << 4))];
    }
#pragma unroll
    for (int ni = 0; ni < NI; ++ni) {
      int c = wc + ni * 16 + lr;
      b[ni] = *(const bf16x8*)&BsB[c * 256 + ((ks * 64 + lk) ^ ((c & 15) << 4))];
    }
#pragma unroll
    for (int mi = 0; mi < 2; ++mi)
#pragma unroll
      for (int ni = 0; ni < NI; ++ni)
        acc[mi][ni] = __builtin_amdgcn_mfma_f32_16x16x32_bf16(a[mi], b[ni],
                                                              acc[mi][ni], 0, 0, 0);
  }

#pragma unroll
  for (int mi = 0; mi < 2; ++mi) {
#pragma unroll
    for (int reg = 0; reg < 4; ++reg) {
      int gr = row0 + wr + mi * 16 + (l >> 4) * 4 + reg;
      if (gr < n) {
#pragma unroll
        for (int ni = 0; ni < NI; ++ni) {
          int gc = wc + ni * 16 + lr;
          Y[(size_t)gr * HOUT + gc] = f2b(acc[mi][ni][reg]);
        }
      }
    }
  }
}

// ---- fused agg(+BN+relu) -> LDS tile -> MFMA GEMM -> next H ---------------
// Block = 64 nodes, 4 waves x 16 nodes. Aggregates H (N x 128 bf16), applies
// BN fold, writes bf16 rows to swizzled LDS tile, then computes tile @ Wt.
template <int NTOUT>
__global__ __launch_bounds__(256) void aggmm_kernel(
    const unsigned short* __restrict__ h, const int* __restrict__ rowptr,
    const int* __restrict__ col, const float* __restrict__ dinv,
    const float* __restrict__ sc, const float* __restrict__ sh,
    const unsigned short* __restrict__ Wt, unsigned short* __restrict__ Y,
    int n_nodes) {
  __shared__ unsigned char ytile[64 * 256];
  __shared__ unsigned char BsB[NTOUT * 256];
  const uint2* hu2 = (const uint2*)h;  // 4 bf16 per uint2, row = 32 uint2
  int t = threadIdx.x;
  int wv = t >> 6, lane = t & 63;
  int row0 = blockIdx.x * 64;

  // stage B (Wt[NTOUT][128] bf16, swizzled)
#pragma unroll
  for (int jj = 0; jj < NTOUT / 16; ++jj) {
    int f = t + 256 * jj; int c = f >> 4, kq = f & 15;
    uint4 v = *(const uint4*)&Wt[(size_t)c * 128 + kq * 8];
    *(uint4*)&BsB[c * 256 + ((kq * 16) ^ ((c & 15) << 4))] = v;
  }

  int phase = lane >> 5;  // NPH = 2
  int sub = lane & 31;    // 32 col-lanes x uint2 = 128 cols

  for (int i = 0; i < 16; ++i) {
    int r = wv * 16 + i;
    int n = row0 + r;
    float a0 = 0.f, a1 = 0.f, a2 = 0.f, a3 = 0.f;
    if (n < n_nodes) {
      float dn = dinv[n];
      int beg = rowptr[n], end = rowptr[n + 1];
      if (phase == 0) {
        uint2 sp = hu2[(size_t)n * 32 + sub];
        float sw = dn * dn;
        a0 = sw * blo(sp.x); a1 = sw * bhi(sp.x);
        a2 = sw * blo(sp.y); a3 = sw * bhi(sp.y);
      }
      int j = beg + phase;
      for (; j + 6 < end; j += 8) {
        int s0 = col[j], s1 = col[j + 2], s2 = col[j + 4], s3 = col[j + 6];
        uint2 h0 = hu2[(size_t)s0 * 32 + sub];
        uint2 h1 = hu2[(size_t)s1 * 32 + sub];
        uint2 h2 = hu2[(size_t)s2 * 32 + sub];
        uint2 h3 = hu2[(size_t)s3 * 32 + sub];
        float w0 = dn * dinv[s0], w1 = dn * dinv[s1];
        float w2 = dn * dinv[s2], w3 = dn * dinv[s3];
        a0 = fmaf(w0, blo(h0.x), a0); a1 = fmaf(w0, bhi(h0.x), a1);
        a2 = fmaf(w0, blo(h0.y), a2); a3 = fmaf(w0, bhi(h0.y), a3);
        a0 = fmaf(w1, blo(h1.x), a0); a1 = fmaf(w1, bhi(h1.x), a1);
        a2 = fmaf(w1, blo(h1.y), a2); a3 = fmaf(w1, bhi(h1.y), a3);
        a0 = fmaf(w2, blo(h2.x), a0); a1 = fmaf(w2, bhi(h2.x), a1);
        a2 = fmaf(w2, blo(h2.y), a2); a3 = fmaf(w2, bhi(h2.y), a3);
        a0 = fmaf(w3, blo(h3.x), a0); a1 = fmaf(w3, bhi(h3.x), a1);
        a2 = fmaf(w3, blo(h3.y), a2); a3 = fmaf(w3, bhi(h3.y), a3);
      }
      for (; j < end; j += 2) {
        int s = col[j];
        uint2 hv = hu2[(size_t)s * 32 + sub];
        float w = dn * dinv[s];
        a0 = fmaf(w, blo(hv.x), a0); a1 = fmaf(w, bhi(hv.x), a1);
        a2 = fmaf(w, blo(hv.y), a2); a3 = fmaf(w, bhi(hv.y), a3);
      }
    }
    // cross-phase reduce (2 phases)
    a0 += __shfl_xor(a0, 32); a1 += __shfl_xor(a1, 32);
    a2 += __shfl_xor(a2, 32); a3 += __shfl_xor(a3, 32);
    if (phase == 0) {
      unsigned p0 = 0, p1 = 0;
      if (n < n_nodes) {
        int c0 = sub * 4;
        float y0 = fmaxf(fmaf(a0, sc[c0], sh[c0]), 0.f);
        float y1 = fmaxf(fmaf(a1, sc[c0 + 1], sh[c0 + 1]), 0.f);
        float y2 = fmaxf(fmaf(a2, sc[c0 + 2], sh[c0 + 2]), 0.f);
        float y3 = fmaxf(fmaf(a3, sc[c0 + 3], sh[c0 + 3]), 0.f);
        p0 = (unsigned)f2b(y0) | ((unsigned)f2b(y1) << 16);
        p1 = (unsigned)f2b(y2) | ((unsigned)f2b(y3) << 16);
      }
      // swizzled LDS write: granule q = sub>>1, half = sub&1
      int byte = r * 256 + (((sub >> 1) * 16) ^ ((r & 15) << 4)) + ((sub & 1) * 8);
      *(uint2*)&ytile[byte] = make_uint2(p0, p1);
    }
  }
  __syncthreads();

  // GEMM: ytile(64x128 bf16) @ Wt^T -> Y(64 x NTOUT bf16)
  constexpr int WC = NTOUT / 2;
  constexpr int NI = WC / 16;
  int wr = (wv >> 1) * 32, wc = (wv & 1) * WC;
  int lr = lane & 15, lk = (lane >> 4) * 16;

  f32x4 acc[2][NI] = {};
#pragma unroll
  for (int ks = 0; ks < 4; ++ks) {
    bf16x8 a[2], b[NI];
#pragma unroll
    for (int mi = 0; mi < 2; ++mi) {
      int r = wr + mi * 16 + lr;
      a[mi] = *(const bf16x8*)&ytile[r * 256 + ((ks * 64 + lk) ^ ((r & 15) << 4))];
    }
#pragma unroll
    for (int ni = 0; ni < NI; ++ni) {
      int c = wc + ni * 16 + lr;
      b[ni] = *(const bf16x8*)&BsB[c * 256 + ((ks * 64 + lk) ^ ((c & 15) << 4))];
    }
#pragma unroll
    for (int mi = 0; mi < 2; ++mi)
#pragma unroll
      for (int ni = 0; ni < NI; ++ni)
        acc[mi][ni] = __builtin_amdgcn_mfma_f32_16x16x32_bf16(a[mi], b[ni],
                                                              acc[mi][ni], 0, 0, 0);
  }

#pragma unroll
  for (int mi = 0; mi < 2; ++mi) {
#pragma unroll
    for (int reg = 0; reg < 4; ++reg) {
      int gr = row0 + wr + mi * 16 + (lane >> 4) * 4 + reg;
      if (gr < n_nodes) {
#pragma unroll
        for (int ni = 0; ni < NI; ++ni) {
          int gc = wc + ni * 16 + lr;
          Y[(size_t)gr * NTOUT + gc] = f2b(acc[mi][ni][reg]);
        }
      }
    }
  }
}

// ---- final aggregation (HOUT=64): bias only, f32 out ----------------------
__global__ __launch_bounds__(256) void agg64_kernel(
    const unsigned short* __restrict__ h, const int* __restrict__ rowptr,
    const int* __restrict__ col, const float* __restrict__ dinv,
    const float* __restrict__ bias, float* __restrict__ out, int n_nodes) {
  int n = (blockIdx.x * blockDim.x + threadIdx.x) >> 6;
  if (n >= n_nodes) return;
  int lane = threadIdx.x & 63;
  const uint2* hu2 = (const uint2*)h;  // row = 16 uint2
  int phase = lane >> 4;               // NPH = 4
  int sub = lane & 15;

  float dn = dinv[n];
  int beg = rowptr[n], end = rowptr[n + 1];
  float a0 = 0.f, a1 = 0.f, a2 = 0.f, a3 = 0.f;
  if (phase == 0) {
    uint2 sp = hu2[(size_t)n * 16 + sub];
    float sw = dn * dn;
    a0 = sw * blo(sp.x); a1 = sw * bhi(sp.x);
    a2 = sw * blo(sp.y); a3 = sw * bhi(sp.y);
  }
  int j = beg + phase;
  for (; j + 12 < end; j += 16) {
    int s0 = col[j], s1 = col[j + 4], s2 = col[j + 8], s3 = col[j + 12];
    uint2 h0 = hu2[(size_t)s0 * 16 + sub];
    uint2 h1 = hu2[(size_t)s1 * 16 + sub];
    uint2 h2 = hu2[(size_t)s2 * 16 + sub];
    uint2 h3 = hu2[(size_t)s3 * 16 + sub];
    float w0 = dn * dinv[s0], w1 = dn * dinv[s1];
    float w2 = dn * dinv[s2], w3 = dn * dinv[s3];
    a0 = fmaf(w0, blo(h0.x), a0); a1 = fmaf(w0, bhi(h0.x), a1);
    a2 = fmaf(w0, blo(h0.y), a2); a3 = fmaf(w0, bhi(h0.y), a3);
    a0 = fmaf(w1, blo(h1.x), a0); a1 = fmaf(w1, bhi(h1.x), a1);
    a2 = fmaf(w1, blo(h1.y), a2); a3 = fmaf(w1, bhi(h1.y), a3);
    a0 = fmaf(w2, blo(h2.x), a0); a1 = fmaf(w2, bhi(h2.x), a1);
    a2 = fmaf(w2, blo(h2.y), a2); a3 = fmaf(w2, bhi(h2.y), a3);
    a0 = fmaf(w3, blo(h3.x), a0); a1 = fmaf(w3, bhi(h3.x), a1);
    a2 = fmaf(w3, blo(h3.y), a2); a3 = fmaf(w3, bhi(h3.y), a3);
  }
  for (; j < end; j += 4) {
    int s = col[j];
    uint2 hv = hu2[(size_t)s * 16 + sub];
    float w = dn * dinv[s];
    a0 = fmaf(w, blo(hv.x), a0); a1 = fmaf(w, bhi(hv.x), a1);
    a2 = fmaf(w, blo(hv.y), a2); a3 = fmaf(w, bhi(hv.y), a3);
  }
  a0 += __shfl_xor(a0, 32); a1 += __shfl_xor(a1, 32);
  a2 += __shfl_xor(a2, 32); a3 += __shfl_xor(a3, 32);
  a0 += __shfl_xor(a0, 16); a1 += __shfl_xor(a1, 16);
  a2 += __shfl_xor(a2, 16); a3 += __shfl_xor(a3, 16);
  if (phase != 0) return;
  int c0 = sub * 4;
  float4 o;
  o.x = a0 + bias[c0];     o.y = a1 + bias[c0 + 1];
  o.z = a2 + bias[c0 + 2]; o.w = a3 + bias[c0 + 3];
  *(float4*)&out[(size_t)n * 64 + c0] = o;
}

extern "C" void kernel_launch(void* const* d_in, const int* in_sizes, int n_in,
                              void* d_out, int out_size, void* d_ws, size_t ws_size,
                              hipStream_t stream) {
  const float* x = (const float*)d_in[0];
  const int* ei32 = (const int*)d_in[1];
  const long long* ei64 = (const long long*)d_in[1];
  const float* W1 = (const float*)d_in[2];
  const float* b1 = (const float*)d_in[3];
  const float* g1 = (const float*)d_in[4];
  const float* be1 = (const float*)d_in[5];
  const float* m1 = (const float*)d_in[6];
  const float* v1 = (const float*)d_in[7];
  const float* W2 = (const float*)d_in[8];
  const float* b2 = (const float*)d_in[9];
  const float* g2 = (const float*)d_in[10];
  const float* be2 = (const float*)d_in[11];
  const float* m2 = (const float*)d_in[12];
  const float* v2 = (const float*)d_in[13];
  const float* W3 = (const float*)d_in[14];
  const float* b3 = (const float*)d_in[15];

  const int N = in_sizes[0] / 128;        // 50000
  const int E = in_sizes[1] / 2;          // 800000
  const int NBK = (N + BWID - 1) / BWID;  // 196 (<= 256)
  const int NC = NBK * NCHUNK;            // 50176

  char* ws = (char*)d_ws;
  size_t off = 0;
  auto alloc = [&](size_t bytes) -> void* {
    void* p = ws + off;
    off = (off + bytes + 255) & ~(size_t)255;
    return p;
  };
  float* dinv = (float*)alloc((size_t)N * 4);
  int* rowptr = (int*)alloc((size_t)(N + 1) * 4);
  int* counts = (int*)alloc((size_t)(NC + 1) * 4);
  int* offs = (int*)alloc((size_t)(NC + 1) * 4);
  int* col = (int*)alloc((size_t)E * 4);
  unsigned* pairs = (unsigned*)alloc((size_t)E * 4);
  int* bsum = (int*)alloc(64 * 4);
  unsigned short* wt1 = (unsigned short*)alloc(128 * 128 * 2);
  unsigned short* wt2 = (unsigned short*)alloc(128 * 128 * 2);
  unsigned short* wt3 = (unsigned short*)alloc(128 * 64 * 2);
  float* sc1 = (float*)alloc(128 * 4);
  float* sh1 = (float*)alloc(128 * 4);
  float* sc2 = (float*)alloc(128 * 4);
  float* sh2 = (float*)alloc(128 * 4);
  unsigned short* hbufA = (unsigned short*)alloc((size_t)N * 128 * 2);  // H1
  unsigned short* hbufB = (unsigned short*)alloc((size_t)N * 128 * 2);  // H2
  unsigned short* hbufC = (unsigned short*)alloc((size_t)N * 64 * 2);   // H3
  (void)ws_size;

  // CSR build + weight prep
  histprep_kernel<<<NCHUNK + 161, 256, 0, stream>>>(
      ei32, ei64, counts, E, NBK,
      W1, W2, W3, b1, g1, be1, m1, v1, b2, g2, be2, m2, v2,
      wt1, wt2, wt3, sc1, sh1, sc2, sh2);
  int nbC = (NC + SCAN_CHUNK - 1) / SCAN_CHUNK;  // 49
  scan_partial_kernel<<<nbC, 256, 0, stream>>>(counts, bsum, NC);
  scan_write_kernel<<<nbC, 256, 0, stream>>>(counts, bsum, offs, NC, nbC);
  bin_scatter_kernel<<<NCHUNK, 256, 0, stream>>>(ei32, ei64, offs, pairs, E, NBK);
  bucket_merged_kernel<<<NBK, 256, 0, stream>>>(pairs, offs, rowptr, dinv,
                                                col, E, N, NBK);

  int gb = (N + 63) / 64;   // 782
  int ab = (N + 3) / 4;     // agg64: one wave per node

  // layer 1 GEMM, then fused agg+GEMM for layers 2 and 3, then final agg
  mgemm_kernel<128><<<gb, 256, 0, stream>>>(x, wt1, hbufA, N);
  aggmm_kernel<128><<<gb, 256, 0, stream>>>(hbufA, rowptr, col, dinv,
                                            sc1, sh1, wt2, hbufB, N);
  aggmm_kernel<64><<<gb, 256, 0, stream>>>(hbufB, rowptr, col, dinv,
                                           sc2, sh2, wt3, hbufC, N);
  agg64_kernel<<<ab, 256, 0, stream>>>(hbufC, rowptr, col, dinv, b3,
                                       (float*)d_out, N);
}

// Round 14
// 165.306 us; speedup vs baseline: 1.4371x; 1.4371x over previous
//
#include <hip/hip_runtime.h>

// ---------------------------------------------------------------------------
// GCN 3-layer fused pipeline for MI355X.  (Round-12 configuration — best.)
//   Layer l: H = bf16mfma(A_bf16 @ Wl_bf16) -> hbuf (bf16)
//   agg[n]  = dinv[n]^2*H[n] + sum_{e:dst=n} dinv[src]*dinv[n]*H[src]  (f32)
//   y = BN/bias epilogue (folded scale/shift) -> bf16 (L1,L2) / f32 (L3)
// CSR: col-only (4B/edge); weights recomputed in agg from L2-resident dinv.
// Build: histprep (hist + fused wprep) -> scan -> scatter -> bucket_merged.
// 11 dispatches.
// ---------------------------------------------------------------------------

#define SCAN_CHUNK 1024
#define NCHUNK 256   // edge chunks (hist/scatter blocks)
#define BSHIFT 8     // dsts per bucket = 256
#define BWID 256
#define ECAP 8192    // LDS col stage capacity per bucket (mean ~4100)

typedef __attribute__((ext_vector_type(8))) short bf16x8;
typedef __attribute__((ext_vector_type(4))) float f32x4;

__device__ __forceinline__ float blo(unsigned p) { return __uint_as_float(p << 16); }
__device__ __forceinline__ float bhi(unsigned p) { return __uint_as_float(p & 0xffff0000u); }
__device__ __forceinline__ unsigned short f2b(float f) {
  unsigned u = __float_as_uint(f);
  unsigned r = (u + 0x7fffu + ((u >> 16) & 1u)) >> 16;  // RTNE
  return (unsigned short)r;
}

// ---- pass A: per-chunk bucket histogram + fused weight prep ---------------
// Blocks [0, NCHUNK): histogram. Blocks [NCHUNK, NCHUNK+161): wprep/BN fold.
__global__ __launch_bounds__(256) void histprep_kernel(
    const int* __restrict__ ei32, const long long* __restrict__ ei64,
    int* __restrict__ counts, int E, int nbk,
    const float* __restrict__ W1, const float* __restrict__ W2,
    const float* __restrict__ W3,
    const float* __restrict__ b1, const float* __restrict__ g1,
    const float* __restrict__ be1, const float* __restrict__ m1,
    const float* __restrict__ v1,
    const float* __restrict__ b2, const float* __restrict__ g2,
    const float* __restrict__ be2, const float* __restrict__ m2,
    const float* __restrict__ v2,
    unsigned short* __restrict__ Wt1, unsigned short* __restrict__ Wt2,
    unsigned short* __restrict__ Wt3,
    float* __restrict__ sc1, float* __restrict__ sh1,
    float* __restrict__ sc2, float* __restrict__ sh2) {
  __shared__ int hist[BWID];
  __shared__ int s_is32;
  int k = blockIdx.x, t = threadIdx.x;
  if (k >= NCHUNK) {  // weight-prep tail
    int i = (k - NCHUNK) * 256 + t;
    if (i < 16384) {
      int kk = i >> 7, c = i & 127;
      Wt1[c * 128 + kk] = f2b(W1[i]);
    } else if (i < 32768) {
      int j = i - 16384; int kk = j >> 7, c = j & 127;
      Wt2[c * 128 + kk] = f2b(W2[j]);
    } else if (i < 40960) {
      int j = i - 32768; int kk = j >> 6, c = j & 63;
      Wt3[c * 128 + kk] = f2b(W3[j]);
    } else if (i < 41088) {
      int c = i - 40960;
      float s = g1[c] * rsqrtf(v1[c] + 1e-5f);
      sc1[c] = s; sh1[c] = (b1[c] - m1[c]) * s + be1[c];
    } else if (i < 41216) {
      int c = i - 41088;
      float s = g2[c] * rsqrtf(v2[c] + 1e-5f);
      sc2[c] = s; sh2[c] = (b2[c] - m2[c]) * s + be2[c];
    }
    return;
  }
  hist[t] = 0;
  if (t == 0) s_is32 = 0;
  int CH = (E + NCHUNK - 1) / NCHUNK;
  int e0 = k * CH, e1 = min(e0 + CH, E);
  __syncthreads();
  // int64 data: odd words are high halves == 0; int32: random node ids.
  if (t < 64 && e0 + t < E && ei32[2 * (e0 + t) + 1] != 0) atomicOr(&s_is32, 1);
  __syncthreads();
  int is32 = s_is32;
  for (int e = e0 + t; e < e1; e += 256) {
    int d = is32 ? ei32[E + e] : (int)ei64[E + e];
    atomicAdd(&hist[d >> BSHIFT], 1);
  }
  __syncthreads();
  if (t < nbk) counts[t * NCHUNK + k] = hist[t];
}

// ---- scan: partial sums ----------------------------------------------------
__global__ __launch_bounds__(256) void scan_partial_kernel(
    const int* __restrict__ src, int* __restrict__ bsum, int n) {
  __shared__ int wsum[4];
  int b = blockIdx.x, t = threadIdx.x;
  int lane = t & 63, wv = t >> 6;
  int i0 = b * SCAN_CHUNK + t * 4;
  int4 d4 = make_int4(0, 0, 0, 0);
  if (i0 + 3 < n) d4 = *(const int4*)&src[i0];
  else {
    if (i0 < n) d4.x = src[i0];
    if (i0 + 1 < n) d4.y = src[i0 + 1];
    if (i0 + 2 < n) d4.z = src[i0 + 2];
  }
  int s = d4.x + d4.y + d4.z + d4.w;
#pragma unroll
  for (int off = 32; off; off >>= 1) s += __shfl_xor(s, off);
  if (lane == 0) wsum[wv] = s;
  __syncthreads();
  if (t == 0) bsum[b] = wsum[0] + wsum[1] + wsum[2] + wsum[3];
}

// ---- scan: write (inline bsum scan; wave 0 redundantly scans <=64 sums) ---
__global__ __launch_bounds__(256) void scan_write_kernel(
    const int* __restrict__ src, const int* __restrict__ bsum,
    int* __restrict__ outp, int n, int nb) {
  __shared__ int woff[4];
  __shared__ int s_boff;
  int b = blockIdx.x, t = threadIdx.x;
  int lane = t & 63, wv = t >> 6;
  if (t < 64) {
    int v = (t < nb) ? bsum[t] : 0;
    int ic = v;
#pragma unroll
    for (int off = 1; off < 64; off <<= 1) {
      int u = __shfl_up(ic, off);
      if (t >= off) ic += u;
    }
    if (t == b) s_boff = ic - v;
    if (b == nb - 1 && t == 63) outp[n] = ic;  // total
  }
  int i0 = b * SCAN_CHUNK + t * 4;
  int4 d4 = make_int4(0, 0, 0, 0);
  if (i0 + 3 < n) d4 = *(const int4*)&src[i0];
  else {
    if (i0 < n) d4.x = src[i0];
    if (i0 + 1 < n) d4.y = src[i0 + 1];
    if (i0 + 2 < n) d4.z = src[i0 + 2];
  }
  int tsum = d4.x + d4.y + d4.z + d4.w;
  int inc = tsum;
#pragma unroll
  for (int off = 1; off < 64; off <<= 1) {
    int u = __shfl_up(inc, off);
    if (lane >= off) inc += u;
  }
  if (lane == 63) woff[wv] = inc;
  __syncthreads();
  if (t == 0) {
    int r = 0;
#pragma unroll
    for (int w = 0; w < 4; ++w) { int sw = woff[w]; woff[w] = r; r += sw; }
  }
  __syncthreads();
  int p = inc - tsum + woff[wv] + s_boff;
  int dg[4] = {d4.x, d4.y, d4.z, d4.w};
#pragma unroll
  for (int j = 0; j < 4; ++j) {
    int i = i0 + j;
    if (i < n) outp[i] = p;
    p += dg[j];
  }
}

// ---- pass C: scatter packed (src | dst_low<<20) into bucketed runs --------
__global__ __launch_bounds__(256) void bin_scatter_kernel(
    const int* __restrict__ ei32, const long long* __restrict__ ei64,
    const int* __restrict__ offs, unsigned* __restrict__ pairs, int E, int nbk) {
  __shared__ int cur[BWID];
  __shared__ int s_is32;
  int k = blockIdx.x, t = threadIdx.x;
  if (t < nbk) cur[t] = offs[t * NCHUNK + k];
  if (t == 0) s_is32 = 0;
  int CH = (E + NCHUNK - 1) / NCHUNK;
  int e0 = k * CH, e1 = min(e0 + CH, E);
  __syncthreads();
  if (t < 64 && e0 + t < E && ei32[2 * (e0 + t) + 1] != 0) atomicOr(&s_is32, 1);
  __syncthreads();
  int is32 = s_is32;
  for (int e = e0 + t; e < e1; e += 256) {
    int s, d;
    if (is32) { s = ei32[e]; d = ei32[E + e]; }
    else      { s = (int)ei64[e]; d = (int)ei64[E + e]; }
    int pos = atomicAdd(&cur[d >> BSHIFT], 1);
    pairs[pos] = (unsigned)s | ((unsigned)(d & (BWID - 1)) << 20);
  }
}

// ---- merged bucket pass: deg -> LDS scan -> rowptr/dinv -> col assembly ---
__global__ __launch_bounds__(256) void bucket_merged_kernel(
    const unsigned* __restrict__ pairs, const int* __restrict__ offs,
    int* __restrict__ rowptr, float* __restrict__ dinv,
    int* __restrict__ col, int E, int n, int nbk) {
  __shared__ int deg[BWID];
  __shared__ int cur[BWID];
  __shared__ int woff[4];
  __shared__ int stage_s[ECAP];
  int b = blockIdx.x, t = threadIdx.x;
  int lane = t & 63, wv = t >> 6;
  deg[t] = 0;
  __syncthreads();
  int basep = offs[b * NCHUNK];
  int endp = (b + 1 < nbk) ? offs[(b + 1) * NCHUNK] : E;
  for (int i = basep + t; i < endp; i += 256)
    atomicAdd(&deg[pairs[i] >> 20], 1);
  __syncthreads();
  int dg = deg[t];
  int inc = dg;
#pragma unroll
  for (int off = 1; off < 64; off <<= 1) {
    int u = __shfl_up(inc, off);
    if (lane >= off) inc += u;
  }
  if (lane == 63) woff[wv] = inc;
  __syncthreads();
  if (t == 0) {
    int r = 0;
#pragma unroll
    for (int w = 0; w < 4; ++w) { int sw = woff[w]; woff[w] = r; r += sw; }
  }
  __syncthreads();
  int exc = inc - dg + woff[wv];
  int idx = b * BWID + t;
  if (idx < n) {
    rowptr[idx] = basep + exc;
    dinv[idx] = rsqrtf((float)(dg + 1));  // +1 self loop
  }
  cur[t] = exc;
  __syncthreads();
  for (int i = basep + t; i < endp; i += 256) {
    unsigned p = pairs[i];
    int s = (int)(p & 0xFFFFFu);
    int dl = (int)(p >> 20);
    int pos = atomicAdd(&cur[dl], 1);
    if (pos < ECAP) stage_s[pos] = s;
    else col[basep + pos] = s;
  }
  __syncthreads();
  int nE = endp - basep;
  int lim = min(nE, ECAP);
  for (int i = t; i < lim; i += 256) col[basep + i] = stage_s[i];
  if (b == 0 && t == 0) rowptr[n] = E;
}

// ---- MFMA bf16 GEMM: Y[n x HOUT](bf16) = A[n x 128] * Wt^T ----------------
template <int HOUT, int ABF16>
__global__ __launch_bounds__(256) void mgemm_kernel(
    const void* __restrict__ Ain, const unsigned short* __restrict__ Wt,
    unsigned short* __restrict__ Y, int n) {
  constexpr int NT = HOUT;
  __shared__ unsigned char AsB[64 * 256];
  __shared__ unsigned char BsB[NT * 256];
  int t = threadIdx.x;
  int row0 = blockIdx.x * 64;

  if constexpr (ABF16) {
    const unsigned short* A = (const unsigned short*)Ain;
#pragma unroll
    for (int jj = 0; jj < 4; ++jj) {
      int f = t + 256 * jj; int r = f >> 4, kq = f & 15;
      uint4 v = make_uint4(0, 0, 0, 0);
      if (row0 + r < n) v = *(const uint4*)&A[(size_t)(row0 + r) * 128 + kq * 8];
      *(uint4*)&AsB[r * 256 + ((kq * 16) ^ ((r & 15) << 4))] = v;
    }
  } else {
    const float* A = (const float*)Ain;
#pragma unroll
    for (int jj = 0; jj < 8; ++jj) {
      int f = t + 256 * jj; int r = f >> 5, kq = f & 31;
      float4 v = make_float4(0.f, 0.f, 0.f, 0.f);
      if (row0 + r < n) v = *(const float4*)&A[(size_t)(row0 + r) * 128 + kq * 4];
      unsigned two0 = (unsigned)f2b(v.x) | ((unsigned)f2b(v.y) << 16);
      unsigned two1 = (unsigned)f2b(v.z) | ((unsigned)f2b(v.w) << 16);
      uint2 o = make_uint2(two0, two1);
      *(uint2*)&AsB[r * 256 + ((kq * 8) ^ ((r & 15) << 4))] = o;
    }
  }
#pragma unroll
  for (int jj = 0; jj < NT / 16; ++jj) {
    int f = t + 256 * jj; int c = f >> 4, kq = f & 15;
    uint4 v = *(const uint4*)&Wt[(size_t)c * 128 + kq * 8];
    *(uint4*)&BsB[c * 256 + ((kq * 16) ^ ((c & 15) << 4))] = v;
  }
  __syncthreads();

  int l = t & 63, wid = t >> 6;
  constexpr int WC = NT / 2;
  constexpr int NI = WC / 16;
  int wr = (wid >> 1) * 32, wc = (wid & 1) * WC;
  int lr = l & 15, lk = (l >> 4) * 16;

  f32x4 acc[2][NI] = {};
#pragma unroll
  for (int ks = 0; ks < 4; ++ks) {
    bf16x8 a[2], b[NI];
#pragma unroll
    for (int mi = 0; mi < 2; ++mi) {
      int r = wr + mi * 16 + lr;
      a[mi] = *(const bf16x8*)&AsB[r * 256 + ((ks * 64 + lk) ^ ((r & 15) << 4))];
    }
#pragma unroll
    for (int ni = 0; ni < NI; ++ni) {
      int c = wc + ni * 16 + lr;
      b[ni] = *(const bf16x8*)&BsB[c * 256 + ((ks * 64 + lk) ^ ((c & 15) << 4))];
    }
#pragma unroll
    for (int mi = 0; mi < 2; ++mi)
#pragma unroll
      for (int ni = 0; ni < NI; ++ni)
        acc[mi][ni] = __builtin_amdgcn_mfma_f32_16x16x32_bf16(a[mi], b[ni],
                                                              acc[mi][ni], 0, 0, 0);
  }

#pragma unroll
  for (int mi = 0; mi < 2; ++mi) {
#pragma unroll
    for (int reg = 0; reg < 4; ++reg) {
      int gr = row0 + wr + mi * 16 + (l >> 4) * 4 + reg;
      if (gr < n) {
#pragma unroll
        for (int ni = 0; ni < NI; ++ni) {
          int gc = wc + ni * 16 + lr;
          Y[(size_t)gr * HOUT + gc] = f2b(acc[mi][ni][reg]);
        }
      }
    }
  }
}

// ---- aggregation: wave/node, edge-phased lanes, uint2 (4 bf16)/lane -------
// col-only CSR; w = dinv[n]*dinv[src] recomputed (dinv is L2-resident).
template <int HOUT, bool BN, bool OUTBF>
__global__ __launch_bounds__(256) void agg_kernel(
    const unsigned short* __restrict__ h, const int* __restrict__ rowptr,
    const int* __restrict__ col, const float* __restrict__ dinv,
    const float* __restrict__ sc, const float* __restrict__ sh,
    void* __restrict__ out, int n_nodes) {
  int n = (blockIdx.x * blockDim.x + threadIdx.x) >> 6;
  if (n >= n_nodes) return;
  int lane = threadIdx.x & 63;
  const uint2* hu2 = (const uint2*)h;         // 4 bf16 per uint2
  constexpr int RW2 = HOUT / 4;               // uint2 per row (32 or 16)
  constexpr int NPH = (HOUT == 128) ? 2 : 4;  // edge phases per wave
  constexpr int GL = 64 / NPH;                // lanes per phase (32 or 16)
  int phase = lane / GL;
  int sub = lane & (GL - 1);

  float dn = dinv[n];
  int beg = rowptr[n], end = rowptr[n + 1];
  float a0 = 0.f, a1 = 0.f, a2 = 0.f, a3 = 0.f;
  if (phase == 0) {
    uint2 sp = hu2[(size_t)n * RW2 + sub];
    float sw = dn * dn;
    a0 = sw * blo(sp.x); a1 = sw * bhi(sp.x);
    a2 = sw * blo(sp.y); a3 = sw * bhi(sp.y);
  }

  int j = beg + phase;
  for (; j + 3 * NPH < end; j += 4 * NPH) {
    int s0 = col[j],           s1 = col[j + NPH];
    int s2 = col[j + 2 * NPH], s3 = col[j + 3 * NPH];
    uint2 h0 = hu2[(size_t)s0 * RW2 + sub];
    uint2 h1 = hu2[(size_t)s1 * RW2 + sub];
    uint2 h2 = hu2[(size_t)s2 * RW2 + sub];
    uint2 h3 = hu2[(size_t)s3 * RW2 + sub];
    float w0 = dn * dinv[s0], w1 = dn * dinv[s1];
    float w2 = dn * dinv[s2], w3 = dn * dinv[s3];
    a0 = fmaf(w0, blo(h0.x), a0); a1 = fmaf(w0, bhi(h0.x), a1);
    a2 = fmaf(w0, blo(h0.y), a2); a3 = fmaf(w0, bhi(h0.y), a3);
    a0 = fmaf(w1, blo(h1.x), a0); a1 = fmaf(w1, bhi(h1.x), a1);
    a2 = fmaf(w1, blo(h1.y), a2); a3 = fmaf(w1, bhi(h1.y), a3);
    a0 = fmaf(w2, blo(h2.x), a0); a1 = fmaf(w2, bhi(h2.x), a1);
    a2 = fmaf(w2, blo(h2.y), a2); a3 = fmaf(w2, bhi(h2.y), a3);
    a0 = fmaf(w3, blo(h3.x), a0); a1 = fmaf(w3, bhi(h3.x), a1);
    a2 = fmaf(w3, blo(h3.y), a2); a3 = fmaf(w3, bhi(h3.y), a3);
  }
  for (; j < end; j += NPH) {
    int s = col[j];
    uint2 hv = hu2[(size_t)s * RW2 + sub];
    float w = dn * dinv[s];
    a0 = fmaf(w, blo(hv.x), a0); a1 = fmaf(w, bhi(hv.x), a1);
    a2 = fmaf(w, blo(hv.y), a2); a3 = fmaf(w, bhi(hv.y), a3);
  }

  // cross-phase reduction
  a0 += __shfl_xor(a0, 32); a1 += __shfl_xor(a1, 32);
  a2 += __shfl_xor(a2, 32); a3 += __shfl_xor(a3, 32);
  if constexpr (NPH == 4) {
    a0 += __shfl_xor(a0, 16); a1 += __shfl_xor(a1, 16);
    a2 += __shfl_xor(a2, 16); a3 += __shfl_xor(a3, 16);
  }
  if (phase != 0) return;

  int c0 = sub * 4;
  float y0, y1, y2, y3;
  if constexpr (BN) {
    y0 = fmaxf(fmaf(a0, sc[c0], sh[c0]), 0.f);
    y1 = fmaxf(fmaf(a1, sc[c0 + 1], sh[c0 + 1]), 0.f);
    y2 = fmaxf(fmaf(a2, sc[c0 + 2], sh[c0 + 2]), 0.f);
    y3 = fmaxf(fmaf(a3, sc[c0 + 3], sh[c0 + 3]), 0.f);
  } else {
    y0 = a0 + sh[c0]; y1 = a1 + sh[c0 + 1];
    y2 = a2 + sh[c0 + 2]; y3 = a3 + sh[c0 + 3];
  }
  if constexpr (OUTBF) {
    unsigned p0 = (unsigned)f2b(y0) | ((unsigned)f2b(y1) << 16);
    unsigned p1 = (unsigned)f2b(y2) | ((unsigned)f2b(y3) << 16);
    ((uint2*)out)[(size_t)n * RW2 + sub] = make_uint2(p0, p1);
  } else {
    float4 o; o.x = y0; o.y = y1; o.z = y2; o.w = y3;
    *(float4*)&((float*)out)[(size_t)n * HOUT + c0] = o;
  }
}

extern "C" void kernel_launch(void* const* d_in, const int* in_sizes, int n_in,
                              void* d_out, int out_size, void* d_ws, size_t ws_size,
                              hipStream_t stream) {
  const float* x = (const float*)d_in[0];
  const int* ei32 = (const int*)d_in[1];
  const long long* ei64 = (const long long*)d_in[1];
  const float* W1 = (const float*)d_in[2];
  const float* b1 = (const float*)d_in[3];
  const float* g1 = (const float*)d_in[4];
  const float* be1 = (const float*)d_in[5];
  const float* m1 = (const float*)d_in[6];
  const float* v1 = (const float*)d_in[7];
  const float* W2 = (const float*)d_in[8];
  const float* b2 = (const float*)d_in[9];
  const float* g2 = (const float*)d_in[10];
  const float* be2 = (const float*)d_in[11];
  const float* m2 = (const float*)d_in[12];
  const float* v2 = (const float*)d_in[13];
  const float* W3 = (const float*)d_in[14];
  const float* b3 = (const float*)d_in[15];

  const int N = in_sizes[0] / 128;        // 50000
  const int E = in_sizes[1] / 2;          // 800000
  const int NBK = (N + BWID - 1) / BWID;  // 196 (<= 256)
  const int NC = NBK * NCHUNK;            // 50176

  char* ws = (char*)d_ws;
  size_t off = 0;
  auto alloc = [&](size_t bytes) -> void* {
    void* p = ws + off;
    off = (off + bytes + 255) & ~(size_t)255;
    return p;
  };
  float* dinv = (float*)alloc((size_t)N * 4);
  int* rowptr = (int*)alloc((size_t)(N + 1) * 4);
  int* counts = (int*)alloc((size_t)(NC + 1) * 4);
  int* offs = (int*)alloc((size_t)(NC + 1) * 4);
  int* col = (int*)alloc((size_t)E * 4);
  unsigned* pairs = (unsigned*)alloc((size_t)E * 4);
  int* bsum = (int*)alloc(64 * 4);
  unsigned short* wt1 = (unsigned short*)alloc(128 * 128 * 2);
  unsigned short* wt2 = (unsigned short*)alloc(128 * 128 * 2);
  unsigned short* wt3 = (unsigned short*)alloc(128 * 64 * 2);
  float* sc1 = (float*)alloc(128 * 4);
  float* sh1 = (float*)alloc(128 * 4);
  float* sc2 = (float*)alloc(128 * 4);
  float* sh2 = (float*)alloc(128 * 4);
  unsigned short* hbuf = (unsigned short*)alloc((size_t)N * 128 * 2);  // bf16
  unsigned short* ybuf = (unsigned short*)alloc((size_t)N * 128 * 2);  // bf16
  (void)ws_size;

  // CSR build + weight prep
  histprep_kernel<<<NCHUNK + 161, 256, 0, stream>>>(
      ei32, ei64, counts, E, NBK,
      W1, W2, W3, b1, g1, be1, m1, v1, b2, g2, be2, m2, v2,
      wt1, wt2, wt3, sc1, sh1, sc2, sh2);
  int nbC = (NC + SCAN_CHUNK - 1) / SCAN_CHUNK;  // 49
  scan_partial_kernel<<<nbC, 256, 0, stream>>>(counts, bsum, NC);
  scan_write_kernel<<<nbC, 256, 0, stream>>>(counts, bsum, offs, NC, nbC);
  bin_scatter_kernel<<<NCHUNK, 256, 0, stream>>>(ei32, ei64, offs, pairs, E, NBK);
  bucket_merged_kernel<<<NBK, 256, 0, stream>>>(pairs, offs, rowptr, dinv,
                                                col, E, N, NBK);

  int gb = (N + 63) / 64;
  int ab = (N + 3) / 4;  // one wave per node, 4 waves/block

  // layer 1
  mgemm_kernel<128, 0><<<gb, 256, 0, stream>>>(x, wt1, hbuf, N);
  agg_kernel<128, true, true><<<ab, 256, 0, stream>>>(hbuf, rowptr, col, dinv,
                                                      sc1, sh1, ybuf, N);
  // layer 2
  mgemm_kernel<128, 1><<<gb, 256, 0, stream>>>(ybuf, wt2, hbuf, N);
  agg_kernel<128, true, true><<<ab, 256, 0, stream>>>(hbuf, rowptr, col, dinv,
                                                      sc2, sh2, ybuf, N);
  // layer 3
  mgemm_kernel<64, 1><<<gb, 256, 0, stream>>>(ybuf, wt3, hbuf, N);
  agg_kernel<64, false, false><<<ab, 256, 0, stream>>>(hbuf, rowptr, col, dinv,
                                                       nullptr, b3, d_out, N);
}